// Round 19
// baseline (1188.741 us; speedup 1.0000x reference)
//
#include <hip/hip_runtime.h>
#include <cstdint>
#include <cstddef>

#define TT 2048   // tokens
#define HH 2048   // hidden
#define II 7168   // intermediate
#define EE 8      // experts
#define RR 159    // low rank
#define RPAD 192  // padded low-rank K (3 x 64)
#define ROWS 4096 // total compact rows = 2*TT

typedef __attribute__((ext_vector_type(8))) short bf16x8;
typedef __attribute__((ext_vector_type(4))) short short4v;
typedef __attribute__((ext_vector_type(4))) float f32x4;

__device__ __forceinline__ unsigned short f2bf(float f) {
  unsigned int u = __float_as_uint(f);
  u += 0x7fffu + ((u >> 16) & 1u);   // RNE
  return (unsigned short)(u >> 16);
}
__device__ __forceinline__ float bf2f(unsigned short u) {
  return __uint_as_float(((unsigned int)u) << 16);
}
__device__ __forceinline__ bf16x8 zero8() {
  bf16x8 v;
#pragma unroll
  for (int j = 0; j < 8; j++) v[j] = 0;
  return v;
}
// async global->LDS, 16B per lane. LDS dest = wave-uniform base + lane*16.
__device__ __forceinline__ void gload16(const unsigned short* g, unsigned short* l) {
  __builtin_amdgcn_global_load_lds(
      (const __attribute__((address_space(1))) unsigned int*)g,
      (__attribute__((address_space(3))) unsigned int*)l, 16, 0, 0);
}

// ---------------- U[rows][159] fp32 -> Up[rows][192] bf16 (zero pad) ----------------
__global__ __launch_bounds__(256) void k_upad(const float* __restrict__ U,
                                              unsigned short* __restrict__ Up, int rows) {
  long long idx = (long long)blockIdx.x * 256 + threadIdx.x;
  long long total = (long long)rows * 24;
  if (idx >= total) return;
  int row = (int)(idx / 24), c8 = (int)(idx % 24);
  unsigned short* dp = Up + (size_t)row * RPAD + c8 * 8;
#pragma unroll
  for (int j = 0; j < 8; j++) {
    int c = c8 * 8 + j;
    dp[j] = (c < RR) ? f2bf(U[(size_t)row * RR + c]) : (unsigned short)0;
  }
}

// ---------------- V[e][159][C] fp32 -> Vt[e][C][192] bf16 (transpose + pad) ----------
// Wave reads 256 B contiguous of a V row (64 lanes x 4 B, coalesced); each
// thread owns one output row h and a 48-wide r-range; writes 16 B stores.
__global__ __launch_bounds__(256) void k_vt(const float* __restrict__ V,
                                            unsigned short* __restrict__ Vt, int C) {
  int e = blockIdx.y;
  int h = blockIdx.x * 64 + (threadIdx.x & 63);
  int q = threadIdx.x >> 6;           // 0..3: owns r in [q*48, q*48+48)
  const float* v = V + (size_t)e * RR * C + h;
  unsigned short* o = Vt + ((size_t)e * C + h) * RPAD;
  for (int g = 0; g < 6; g++) {
    int r0 = q * 48 + g * 8;
    bf16x8 pk;
#pragma unroll
    for (int j = 0; j < 8; j++) {
      int r = r0 + j;
      pk[j] = (short)((r < RR) ? f2bf(v[(size_t)r * C]) : (unsigned short)0);
    }
    *(bf16x8*)(o + r0) = pk;
  }
}

// ---------------- merge v4: Wb = bf16(Wf + Upad @ V) ----------------
// Both operands pre-laid-out row-major [*][192] bf16 -> staged via gload16 DMA
// (pre-swizzled source, linear dest), exactly the proven GEMM staging pattern.
// MFMA over K=192 (3 chunks, 2 barriers each); delta -> Dl (aliases Us/Vs);
// per-wave-coalesced fix-up streams W fp32 and writes bf16.
// LDS: Us(16KB)+Vs(16KB) aliased by Dl[128][136] = 34 KB; (256,4) forces
// VGPR<=128 so the LDS limit (4 blocks/CU) is reached (r18 lesson).
__global__ __launch_bounds__(256, 4) void k_merge(
    const float* __restrict__ Wf, const unsigned short* __restrict__ Upad,
    const unsigned short* __restrict__ Vtg, unsigned short* __restrict__ Wb,
    int M2, int C) {
  int e = blockIdx.z;
  int row0 = blockIdx.y * 128;
  int col0 = blockIdx.x * 128;
  const float* w = Wf + (size_t)e * M2 * C;
  const unsigned short* up = Upad + (size_t)e * M2 * RPAD;
  const unsigned short* vt = Vtg + (size_t)e * C * RPAD;
  unsigned short* wb = Wb + (size_t)e * M2 * C;
  __shared__ unsigned short sbuf[17408];   // 34 KB
  unsigned short* Us = sbuf;               // [128][64] (swizzled layout)
  unsigned short* Vs = sbuf + 8192;        // [128][64] (swizzled layout)
  unsigned short* Dl = sbuf;               // [128][136] bf16 delta (aliases)
  int tid = threadIdx.x, lane = tid & 63, wv = tid >> 6;
  int wr = (wv >> 1) * 64, wc = (wv & 1) * 64;
  f32x4 acc[4][4];
#pragma unroll
  for (int m = 0; m < 4; m++)
#pragma unroll
    for (int n = 0; n < 4; n++) acc[m][n] = (f32x4){0.f, 0.f, 0.f, 0.f};
  // DMA staging geometry: wave wv covers rows [wv*32, wv*32+32); instr i covers
  // 8 rows; lane -> (row += lane>>3, col-slot lane&7). Source col pre-swizzled.
  int srow = (wv << 5) + (lane >> 3);
  int swz = (((lane & 7) ^ ((lane >> 3) & 7)) << 3);
  const unsigned short* pu[4];
  const unsigned short* pv[4];
#pragma unroll
  for (int i = 0; i < 4; i++) {
    pu[i] = up + (size_t)(row0 + srow + i * 8) * RPAD + swz;
    pv[i] = vt + (size_t)(col0 + srow + i * 8) * RPAD + swz;
  }
  for (int kt = 0; kt < RPAD; kt += 64) {
#pragma unroll
    for (int i = 0; i < 4; i++) {
      gload16(pu[i] + kt, &Us[((wv << 5) + (i << 3)) * 64]);
      gload16(pv[i] + kt, &Vs[((wv << 5) + (i << 3)) * 64]);
    }
    __syncthreads();   // drain DMA; previous MFMA already fenced by loop-end barrier
#pragma unroll
    for (int ks = 0; ks < 2; ks++) {
      bf16x8 af[4], bf[4];
#pragma unroll
      for (int m = 0; m < 4; m++) {
        int r = wr + m * 16 + (lane & 15);
        af[m] = *(const bf16x8*)&Us[r * 64 + (((ks * 4 + (lane >> 4)) ^ (r & 7)) * 8)];
      }
#pragma unroll
      for (int n = 0; n < 4; n++) {
        int r = wc + n * 16 + (lane & 15);
        bf[n] = *(const bf16x8*)&Vs[r * 64 + (((ks * 4 + (lane >> 4)) ^ (r & 7)) * 8)];
      }
#pragma unroll
      for (int m = 0; m < 4; m++)
#pragma unroll
        for (int n = 0; n < 4; n++)
          acc[m][n] = __builtin_amdgcn_mfma_f32_16x16x32_bf16(af[m], bf[n], acc[m][n], 0, 0, 0);
    }
    __syncthreads();   // MFMA done before next stage overwrites Us/Vs
  }
  // stage delta (bf16) into LDS at fragment positions (aliases Us/Vs)
#pragma unroll
  for (int m = 0; m < 4; m++) {
#pragma unroll
    for (int r4 = 0; r4 < 4; r4++) {
      int row = wr + m * 16 + (lane >> 4) * 4 + r4;
#pragma unroll
      for (int n = 0; n < 4; n++) {
        int col = wc + n * 16 + (lane & 15);
        Dl[row * 136 + col] = f2bf(acc[m][n][r4]);
      }
    }
  }
  __syncthreads();
  // fix-up, per-wave coalesced: 32 lanes cover one row (512 B contiguous read,
  // 256 B contiguous write); 8 rows per pass; 16 passes in 4-pass chunks.
  {
    int rr = tid >> 5;        // 0..7: row within pass
    int c4 = (tid & 31) * 4;  // float4 column offset
    for (int pc = 0; pc < 4; pc++) {
#pragma unroll
      for (int p = 0; p < 4; p++) {
        int row = (pc * 4 + p) * 8 + rr;
        const float* src = w + (size_t)(row0 + row) * C + col0 + c4;
        float4 a = *(const float4*)src;
        const unsigned short* dl = &Dl[row * 136 + c4];
        short4v o;
        o[0] = (short)f2bf(a.x + bf2f(dl[0]));
        o[1] = (short)f2bf(a.y + bf2f(dl[1]));
        o[2] = (short)f2bf(a.z + bf2f(dl[2]));
        o[3] = (short)f2bf(a.w + bf2f(dl[3]));
        *(short4v*)(wb + (size_t)(row0 + row) * C + col0 + c4) = o;
      }
    }
  }
}

// ---------------- router (also writes Xb = bf16(x)) ----------------
__global__ __launch_bounds__(256) void k_router(
    const float* __restrict__ x, const float* __restrict__ gw,
    float* __restrict__ logits_out, int* __restrict__ sel,
    float* __restrict__ wtok, int* __restrict__ counts,
    unsigned short* __restrict__ xb) {
  int t = blockIdx.x;
  const float* xr = x + (size_t)t * HH;
  int base = threadIdx.x * 8;
  float4 x0 = *(const float4*)(xr + base);
  float4 x1 = *(const float4*)(xr + base + 4);
  {
    bf16x8 v;
    v[0] = (short)f2bf(x0.x); v[1] = (short)f2bf(x0.y);
    v[2] = (short)f2bf(x0.z); v[3] = (short)f2bf(x0.w);
    v[4] = (short)f2bf(x1.x); v[5] = (short)f2bf(x1.y);
    v[6] = (short)f2bf(x1.z); v[7] = (short)f2bf(x1.w);
    *(bf16x8*)(xb + (size_t)t * HH + base) = v;
  }
  float part[EE];
#pragma unroll
  for (int e = 0; e < EE; e++) {
    const float* g = gw + (size_t)e * HH + base;
    float4 g0 = *(const float4*)g;
    float4 g1 = *(const float4*)(g + 4);
    part[e] = x0.x * g0.x + x0.y * g0.y + x0.z * g0.z + x0.w * g0.w +
              x1.x * g1.x + x1.y * g1.y + x1.z * g1.z + x1.w * g1.w;
  }
#pragma unroll
  for (int off = 32; off > 0; off >>= 1)
#pragma unroll
    for (int e = 0; e < EE; e++) part[e] += __shfl_down(part[e], off);
  __shared__ float red[4][EE];
  int w = threadIdx.x >> 6, lane = threadIdx.x & 63;
  if (lane == 0) {
#pragma unroll
    for (int e = 0; e < EE; e++) red[w][e] = part[e];
  }
  __syncthreads();
  if (threadIdx.x == 0) {
    float lg[EE];
    float mx = -1e30f;
#pragma unroll
    for (int e = 0; e < EE; e++) {
      lg[e] = red[0][e] + red[1][e] + red[2][e] + red[3][e];
      logits_out[(size_t)t * EE + e] = lg[e];
      mx = fmaxf(mx, lg[e]);
    }
    float p[EE];
#pragma unroll
    for (int e = 0; e < EE; e++) p[e] = __expf(lg[e] - mx);
    int i0 = 0;
#pragma unroll
    for (int e = 1; e < EE; e++)
      if (lg[e] > lg[i0]) i0 = e;
    int i1 = (i0 == 0) ? 1 : 0;
#pragma unroll
    for (int e = 0; e < EE; e++)
      if (e != i0 && lg[e] > lg[i1]) i1 = e;
    float s = p[i0] + p[i1];
    sel[t * 2] = i0;
    sel[t * 2 + 1] = i1;
    wtok[t * 2] = p[i0] / s;
    wtok[t * 2 + 1] = p[i1] / s;
    atomicAdd(&counts[i0], 1);
    atomicAdd(&counts[i1], 1);
  }
}

// ---------------- prefix offsets ----------------
__global__ void k_offsets(const int* __restrict__ counts, int* __restrict__ offs,
                          int* __restrict__ curs) {
  if (threadIdx.x == 0 && blockIdx.x == 0) {
    int o = 0;
    for (int e = 0; e < EE; e++) {
      offs[e] = o;
      curs[e] = o;
      o += counts[e];
    }
    offs[EE] = o;
  }
}

// ---------------- build compact expert lists ----------------
__global__ void k_build(const int* __restrict__ sel, const float* __restrict__ wtok,
                        int* __restrict__ curs, int* __restrict__ rowsA,
                        float* __restrict__ rowwgt, int* __restrict__ rowid) {
  int t = blockIdx.x * blockDim.x + threadIdx.x;
  if (t >= TT) return;
  for (int k = 0; k < 2; k++) {
    int e = sel[t * 2 + k];
    int pos = atomicAdd(&curs[e], 1);
    rowsA[pos] = t;
    rowwgt[pos] = wtok[t * 2 + k];
    rowid[t * 2 + k] = pos;
  }
}

// ---------------- MLP1 dual: hmid = silu(X@W1'^T) * (X@W3'^T) ----------------
// All-DMA bf16 staging (proven structure), merged weights, no LR.
__global__ __launch_bounds__(256, 2) void k_mlp1(
    const unsigned short* __restrict__ Xb,
    const unsigned short* __restrict__ W1b, const unsigned short* __restrict__ W3b,
    unsigned short* __restrict__ hmid,
    const int* __restrict__ counts, const int* __restrict__ offs,
    const int* __restrict__ rowsA) {
  int e = blockIdx.z;
  int cnt = counts[e];
  int m0 = blockIdx.y * 128;
  if (m0 >= cnt) return;
  int n0 = blockIdx.x * 128;
  int roff = offs[e];
  __shared__ unsigned short As[128 * 64];
  __shared__ unsigned short Bg[128 * 64];
  __shared__ unsigned short Bu[128 * 64];
  int tid = threadIdx.x, lane = tid & 63, w = tid >> 6;
  int wr = (w >> 1) * 64, wc = (w & 1) * 64;
  f32x4 accg[4][4], accu[4][4];
#pragma unroll
  for (int m = 0; m < 4; m++)
#pragma unroll
    for (int n = 0; n < 4; n++) {
      accg[m][n] = (f32x4){0.f, 0.f, 0.f, 0.f};
      accu[m][n] = (f32x4){0.f, 0.f, 0.f, 0.f};
    }
  int srow = (w << 5) + (lane >> 3);
  int swz = (((lane & 7) ^ ((lane >> 3) & 7)) << 3);
  const unsigned short* pa[4];
  const unsigned short* pg[4];
  const unsigned short* pu[4];
  {
    const unsigned short* w1 = W1b + (size_t)e * II * HH;
    const unsigned short* w3 = W3b + (size_t)e * II * HH;
#pragma unroll
    for (int i = 0; i < 4; i++) {
      int gr = m0 + srow + i * 8;
      if (gr >= cnt) gr = cnt - 1;  // clamp: garbage rows masked at store
      pa[i] = Xb + (size_t)rowsA[roff + gr] * HH + swz;
      pg[i] = w1 + (size_t)(n0 + srow + i * 8) * HH + swz;
      pu[i] = w3 + (size_t)(n0 + srow + i * 8) * HH + swz;
    }
  }
  for (int kt = 0; kt < HH; kt += 64) {
#pragma unroll
    for (int i = 0; i < 4; i++) {
      gload16(pa[i] + kt, &As[((w << 5) + (i << 3)) * 64]);
      gload16(pg[i] + kt, &Bg[((w << 5) + (i << 3)) * 64]);
      gload16(pu[i] + kt, &Bu[((w << 5) + (i << 3)) * 64]);
    }
    __syncthreads();
#pragma unroll
    for (int ks = 0; ks < 2; ks++) {
      bf16x8 af[4], bg[4], bu[4];
#pragma unroll
      for (int m = 0; m < 4; m++) {
        int r = wr + m * 16 + (lane & 15);
        af[m] = *(const bf16x8*)&As[r * 64 + (((ks * 4 + (lane >> 4)) ^ (r & 7)) * 8)];
      }
#pragma unroll
      for (int n = 0; n < 4; n++) {
        int r = wc + n * 16 + (lane & 15);
        int idx = r * 64 + (((ks * 4 + (lane >> 4)) ^ (r & 7)) * 8);
        bg[n] = *(const bf16x8*)&Bg[idx];
        bu[n] = *(const bf16x8*)&Bu[idx];
      }
#pragma unroll
      for (int m = 0; m < 4; m++)
#pragma unroll
        for (int n = 0; n < 4; n++) {
          accg[m][n] = __builtin_amdgcn_mfma_f32_16x16x32_bf16(af[m], bg[n], accg[m][n], 0, 0, 0);
          accu[m][n] = __builtin_amdgcn_mfma_f32_16x16x32_bf16(af[m], bu[n], accu[m][n], 0, 0, 0);
        }
    }
    __syncthreads();
  }
  // epilogue: silu(g) * u -> bf16
#pragma unroll
  for (int m = 0; m < 4; m++) {
#pragma unroll
    for (int r4 = 0; r4 < 4; r4++) {
      int row = m0 + wr + m * 16 + (lane >> 4) * 4 + r4;
      if (row < cnt) {
        size_t rb = (size_t)(roff + row) * II + n0 + wc;
#pragma unroll
        for (int n = 0; n < 4; n++) {
          float g = accg[m][n][r4], uu = accu[m][n][r4];
          float h = (g / (1.f + __expf(-g))) * uu;
          hmid[rb + n * 16 + (lane & 15)] = f2bf(h);
        }
      }
    }
  }
}

// ---------------- MLP2: y = (hmid@W2'^T)*rowwgt -> ybuf (fp32), no LR ---------
__global__ __launch_bounds__(256, 2) void k_mlp2(
    const unsigned short* __restrict__ hmid,
    const unsigned short* __restrict__ W2b,
    const float* __restrict__ rowwgt, float* __restrict__ ybuf,
    const int* __restrict__ counts, const int* __restrict__ offs) {
  int e = blockIdx.z;
  int cnt = counts[e];
  int m0 = blockIdx.y * 128;
  if (m0 >= cnt) return;
  int n0 = blockIdx.x * 128;
  int roff = offs[e];
  __shared__ unsigned short As[128 * 64];
  __shared__ unsigned short Bs[128 * 64];
  int tid = threadIdx.x, lane = tid & 63, w = tid >> 6;
  int wr = (w >> 1) * 64, wc = (w & 1) * 64;
  f32x4 acc[4][4];
#pragma unroll
  for (int m = 0; m < 4; m++)
#pragma unroll
    for (int n = 0; n < 4; n++) acc[m][n] = (f32x4){0.f, 0.f, 0.f, 0.f};
  int srow = (w << 5) + (lane >> 3);
  int swz = (((lane & 7) ^ ((lane >> 3) & 7)) << 3);
  const unsigned short* pa[4];
  const unsigned short* pb[4];
  {
    const unsigned short* w2 = W2b + (size_t)e * HH * II;
#pragma unroll
    for (int i = 0; i < 4; i++) {
      int gr = m0 + srow + i * 8;
      if (gr >= cnt) gr = cnt - 1;
      pa[i] = hmid + (size_t)(roff + gr) * II + swz;
      pb[i] = w2 + (size_t)(n0 + srow + i * 8) * II + swz;
    }
  }
  for (int kt = 0; kt < II; kt += 64) {
#pragma unroll
    for (int i = 0; i < 4; i++) {
      gload16(pa[i] + kt, &As[((w << 5) + (i << 3)) * 64]);
      gload16(pb[i] + kt, &Bs[((w << 5) + (i << 3)) * 64]);
    }
    __syncthreads();
#pragma unroll
    for (int ks = 0; ks < 2; ks++) {
      bf16x8 af[4], bs[4];
#pragma unroll
      for (int m = 0; m < 4; m++) {
        int r = wr + m * 16 + (lane & 15);
        af[m] = *(const bf16x8*)&As[r * 64 + (((ks * 4 + (lane >> 4)) ^ (r & 7)) * 8)];
      }
#pragma unroll
      for (int n = 0; n < 4; n++) {
        int r = wc + n * 16 + (lane & 15);
        bs[n] = *(const bf16x8*)&Bs[r * 64 + (((ks * 4 + (lane >> 4)) ^ (r & 7)) * 8)];
      }
#pragma unroll
      for (int m = 0; m < 4; m++)
#pragma unroll
        for (int n = 0; n < 4; n++)
          acc[m][n] = __builtin_amdgcn_mfma_f32_16x16x32_bf16(af[m], bs[n], acc[m][n], 0, 0, 0);
    }
    __syncthreads();
  }
#pragma unroll
  for (int m = 0; m < 4; m++) {
#pragma unroll
    for (int r4 = 0; r4 < 4; r4++) {
      int row = m0 + wr + m * 16 + (lane >> 4) * 4 + r4;
      if (row < cnt) {
        float wgt = rowwgt[roff + row];
        size_t rb = (size_t)(roff + row) * HH + n0 + wc;
#pragma unroll
        for (int n = 0; n < 4; n++)
          ybuf[rb + n * 16 + (lane & 15)] = acc[m][n][r4] * wgt;
      }
    }
  }
}

// ---------------- combine: out[t] = y[row0] + y[row1] ----------------
__global__ void k_combine(const float* __restrict__ ybuf, const int* __restrict__ rowid,
                          float* __restrict__ out) {
  int idx = blockIdx.x * 256 + threadIdx.x;
  int t = idx >> 8;
  int c = (idx & 255) * 8;
  int r0 = rowid[t * 2], r1 = rowid[t * 2 + 1];
  const float* y0 = ybuf + (size_t)r0 * HH + c;
  const float* y1 = ybuf + (size_t)r1 * HH + c;
  float4 a0 = *(const float4*)y0, a1 = *(const float4*)(y0 + 4);
  float4 b0 = *(const float4*)y1, b1 = *(const float4*)(y1 + 4);
  float4 o0 = {a0.x + b0.x, a0.y + b0.y, a0.z + b0.z, a0.w + b0.w};
  float4 o1 = {a1.x + b1.x, a1.y + b1.y, a1.z + b1.z, a1.w + b1.w};
  float* o = out + (size_t)t * HH + c;
  *(float4*)o = o0;
  *(float4*)(o + 4) = o1;
}

extern "C" void kernel_launch(void* const* d_in, const int* in_sizes, int n_in,
                              void* d_out, int out_size, void* d_ws, size_t ws_size,
                              hipStream_t stream) {
  const float* x  = (const float*)d_in[0];
  const float* gw = (const float*)d_in[1];
  const float* W1 = (const float*)d_in[2];
  const float* W2 = (const float*)d_in[3];
  const float* W3 = (const float*)d_in[4];
  const float* U1 = (const float*)d_in[5];
  const float* V1 = (const float*)d_in[6];
  const float* U2 = (const float*)d_in[7];
  const float* V2 = (const float*)d_in[8];
  const float* U3 = (const float*)d_in[9];
  const float* V3 = (const float*)d_in[10];
  float* out = (float*)d_out;
  float* logits = out + (size_t)TT * HH;

  char* ws = (char*)d_ws;
  size_t off = 0;
  auto take = [&](size_t b) -> char* {
    char* p = ws + off;
    off += (b + 255) & ~(size_t)255;
    return p;
  };
  unsigned short* Xb   = (unsigned short*)take((size_t)TT * HH * 2);
  unsigned short* hmid = (unsigned short*)take((size_t)ROWS * II * 2);
  float* ybuf          = (float*)take((size_t)ROWS * HH * 4);
  int* sel             = (int*)take((size_t)TT * 2 * 4);
  float* wtok          = (float*)take((size_t)TT * 2 * 4);
  int* rowsA           = (int*)take((size_t)ROWS * 4);
  float* rowwgt        = (float*)take((size_t)ROWS * 4);
  int* rowid           = (int*)take((size_t)TT * 2 * 4);
  int* meta            = (int*)take(1024);
  int* counts  = meta;
  int* offs    = meta + 16;
  int* curs    = meta + 32;
  unsigned short* W1b = (unsigned short*)take((size_t)EE * II * HH * 2);
  unsigned short* W3b = (unsigned short*)take((size_t)EE * II * HH * 2);
  unsigned short* W2b = (unsigned short*)take((size_t)EE * HH * II * 2);
  unsigned short* V1t = (unsigned short*)take((size_t)EE * HH * RPAD * 2);
  unsigned short* V3t = (unsigned short*)take((size_t)EE * HH * RPAD * 2);
  unsigned short* V2t = (unsigned short*)take((size_t)EE * II * RPAD * 2);
  unsigned short* U1p = (unsigned short*)take((size_t)EE * II * RPAD * 2);
  unsigned short* U3p = (unsigned short*)take((size_t)EE * II * RPAD * 2);
  unsigned short* U2p = (unsigned short*)take((size_t)EE * HH * RPAD * 2);

  hipMemsetAsync(counts, 0, EE * sizeof(int), stream);
  // preps: U -> padded bf16 [rows][192]; V -> transposed padded bf16 [C][192]
  k_upad<<<(EE * II * 24 + 255) / 256, 256, 0, stream>>>(U1, U1p, EE * II);
  k_upad<<<(EE * II * 24 + 255) / 256, 256, 0, stream>>>(U3, U3p, EE * II);
  k_upad<<<(EE * HH * 24 + 255) / 256, 256, 0, stream>>>(U2, U2p, EE * HH);
  k_vt<<<dim3(HH / 64, EE), 256, 0, stream>>>(V1, V1t, HH);
  k_vt<<<dim3(HH / 64, EE), 256, 0, stream>>>(V3, V3t, HH);
  k_vt<<<dim3(II / 64, EE), 256, 0, stream>>>(V2, V2t, II);
  // merge low-rank delta into bf16 weights: W' = bf16(W + U@V)
  k_merge<<<dim3(HH / 128, II / 128, EE), 256, 0, stream>>>(W1, U1p, V1t, W1b, II, HH);
  k_merge<<<dim3(HH / 128, II / 128, EE), 256, 0, stream>>>(W3, U3p, V3t, W3b, II, HH);
  k_merge<<<dim3(II / 128, HH / 128, EE), 256, 0, stream>>>(W2, U2p, V2t, W2b, HH, II);
  // routing
  k_router<<<TT, 256, 0, stream>>>(x, gw, logits, sel, wtok, counts, Xb);
  k_offsets<<<1, 64, 0, stream>>>(counts, offs, curs);
  k_build<<<TT / 256, 256, 0, stream>>>(sel, wtok, curs, rowsA, rowwgt, rowid);
  // expert MLP (all-DMA bf16 GEMMs, merged weights, no low-rank machinery)
  k_mlp1<<<dim3(II / 128, TT / 128, EE), 256, 0, stream>>>(
      Xb, W1b, W3b, hmid, counts, offs, rowsA);
  k_mlp2<<<dim3(HH / 128, TT / 128, EE), 256, 0, stream>>>(
      hmid, W2b, rowwgt, ybuf, counts, offs);
  k_combine<<<(TT * HH / 8) / 256, 256, 0, stream>>>(ybuf, rowid, out);
}

// Round 20
// 1137.976 us; speedup vs baseline: 1.0446x; 1.0446x over previous
//
#include <hip/hip_runtime.h>
#include <cstdint>
#include <cstddef>

#define TT 2048   // tokens
#define HH 2048   // hidden
#define II 7168   // intermediate
#define EE 8      // experts
#define RR 159    // low rank
#define RPAD 192  // padded low-rank K (3 x 64)
#define ROWS 4096 // total compact rows = 2*TT

typedef __attribute__((ext_vector_type(8))) short bf16x8;
typedef __attribute__((ext_vector_type(4))) short short4v;
typedef __attribute__((ext_vector_type(4))) float f32x4;

__device__ __forceinline__ unsigned short f2bf(float f) {
  unsigned int u = __float_as_uint(f);
  u += 0x7fffu + ((u >> 16) & 1u);   // RNE
  return (unsigned short)(u >> 16);
}
__device__ __forceinline__ float bf2f(unsigned short u) {
  return __uint_as_float(((unsigned int)u) << 16);
}
__device__ __forceinline__ bf16x8 zero8() {
  bf16x8 v;
#pragma unroll
  for (int j = 0; j < 8; j++) v[j] = 0;
  return v;
}
// async global->LDS, 16B per lane. LDS dest = wave-uniform base + lane*16.
__device__ __forceinline__ void gload16(const unsigned short* g, unsigned short* l) {
  __builtin_amdgcn_global_load_lds(
      (const __attribute__((address_space(1))) unsigned int*)g,
      (__attribute__((address_space(3))) unsigned int*)l, 16, 0, 0);
}

// ---------------- fp32 -> bf16 flat convert (V matrices) ----------------
__global__ __launch_bounds__(256) void k_f2bf_flat(const float* __restrict__ s,
                                                   unsigned short* __restrict__ d,
                                                   long long n8) {
  long long i = (long long)blockIdx.x * blockDim.x + threadIdx.x;
  long long stride = (long long)gridDim.x * blockDim.x;
  for (; i < n8; i += stride) {
    const float* p = s + i * 8;
    float4 a = *(const float4*)p;
    float4 b = *(const float4*)(p + 4);
    bf16x8 v;
    v[0] = (short)f2bf(a.x); v[1] = (short)f2bf(a.y);
    v[2] = (short)f2bf(a.z); v[3] = (short)f2bf(a.w);
    v[4] = (short)f2bf(b.x); v[5] = (short)f2bf(b.y);
    v[6] = (short)f2bf(b.z); v[7] = (short)f2bf(b.w);
    *(bf16x8*)(d + i * 8) = v;
  }
}

// ---------------- U[rows][159] fp32 -> Up[rows][192] bf16 (zero pad) ----------------
__global__ __launch_bounds__(256) void k_upad(const float* __restrict__ U,
                                              unsigned short* __restrict__ Up, int rows) {
  long long idx = (long long)blockIdx.x * 256 + threadIdx.x;
  long long total = (long long)rows * 24;
  if (idx >= total) return;
  int row = (int)(idx / 24), c8 = (int)(idx % 24);
  unsigned short* dp = Up + (size_t)row * RPAD + c8 * 8;
#pragma unroll
  for (int j = 0; j < 8; j++) {
    int c = c8 * 8 + j;
    dp[j] = (c < RR) ? f2bf(U[(size_t)row * RR + c]) : (unsigned short)0;
  }
}

// ---------------- merge: Wb = bf16(Wf + Upad @ Vb) (round-15/18 proven) ----------------
// MFMA computes the 128x128 delta tile -> LDS (bf16); then a fix-up pass with
// per-wave-coalesced W reads: 32 lanes cover one row (512 B contiguous), 8 rows
// per pass. LDS alias: Us(8192)+Vt(9216) == Dl[128][136] (34 KB).
// __launch_bounds__(256,4): force VGPR<=128 so the 34-KB-LDS limit (4 blocks/CU)
// is actually reached — the fix-up streaming phase is occupancy-hungry.
__global__ __launch_bounds__(256, 4) void k_merge(
    const float* __restrict__ Wf, const unsigned short* __restrict__ Upad,
    const unsigned short* __restrict__ Vb, unsigned short* __restrict__ Wb,
    int M2, int C) {
  int e = blockIdx.z;
  int row0 = blockIdx.y * 128;
  int col0 = blockIdx.x * 128;
  const float* w = Wf + (size_t)e * M2 * C;
  const unsigned short* up = Upad + (size_t)e * M2 * RPAD;
  const unsigned short* vb = Vb + (size_t)e * RR * C;
  unsigned short* wb = Wb + (size_t)e * M2 * C;
  __shared__ unsigned short sbuf[17408];   // 34 KB
  unsigned short* Us = sbuf;               // [128][64] swizzled
  unsigned short* Vt = sbuf + 8192;        // [128 h][72 r]
  unsigned short* Dl = sbuf;               // [128][136] bf16 delta (aliases Us/Vt)
  int tid = threadIdx.x, lane = tid & 63, wv = tid >> 6;
  int wr = (wv >> 1) * 64, wc = (wv & 1) * 64;
  int rstage = tid >> 3, cg = tid & 7;
  f32x4 acc[4][4];
#pragma unroll
  for (int m = 0; m < 4; m++)
#pragma unroll
    for (int n = 0; n < 4; n++) acc[m][n] = (f32x4){0.f, 0.f, 0.f, 0.f};
  int rl = tid & 15;          // V stage: r within 16-group
  int h8 = (tid >> 4) * 8;    // V stage: 8-h chunk
  for (int kt = 0; kt < RPAD; kt += 64) {
    // U tile [128 rows][64 k], swizzled store
#pragma unroll
    for (int p = 0; p < 4; p++) {
      int r = p * 32 + rstage;
      bf16x8 v = *(const bf16x8*)(up + (size_t)(row0 + r) * RPAD + kt + cg * 8);
      *(bf16x8*)&Us[r * 64 + ((cg ^ (r & 7)) * 8)] = v;
    }
    // V^T tile: Vt[h][r] = V[kt+r][col0+h], zero past RR
#pragma unroll
    for (int rr = 0; rr < 4; rr++) {
      int r = rr * 16 + rl;
      int rg = kt + r;
      bf16x8 v = zero8();
      if (rg < RR) v = *(const bf16x8*)(vb + (size_t)rg * C + col0 + h8);
#pragma unroll
      for (int j = 0; j < 8; j++) Vt[(h8 + j) * 72 + r] = (unsigned short)v[j];
    }
    __syncthreads();
#pragma unroll
    for (int ks = 0; ks < 2; ks++) {
      bf16x8 af[4], bf[4];
#pragma unroll
      for (int m = 0; m < 4; m++) {
        int r = wr + m * 16 + (lane & 15);
        af[m] = *(const bf16x8*)&Us[r * 64 + (((ks * 4 + (lane >> 4)) ^ (r & 7)) * 8)];
      }
#pragma unroll
      for (int n = 0; n < 4; n++) {
        int h = wc + n * 16 + (lane & 15);
        bf[n] = *(const bf16x8*)&Vt[h * 72 + (ks * 4 + (lane >> 4)) * 8];
      }
#pragma unroll
      for (int m = 0; m < 4; m++)
#pragma unroll
        for (int n = 0; n < 4; n++)
          acc[m][n] = __builtin_amdgcn_mfma_f32_16x16x32_bf16(af[m], bf[n], acc[m][n], 0, 0, 0);
    }
    __syncthreads();
  }
  // stage delta (bf16) into LDS at fragment positions (aliases Us/Vt — safe after barrier)
#pragma unroll
  for (int m = 0; m < 4; m++) {
#pragma unroll
    for (int r4 = 0; r4 < 4; r4++) {
      int row = wr + m * 16 + (lane >> 4) * 4 + r4;
#pragma unroll
      for (int n = 0; n < 4; n++) {
        int col = wc + n * 16 + (lane & 15);
        Dl[row * 136 + col] = f2bf(acc[m][n][r4]);
      }
    }
  }
  __syncthreads();
  // fix-up, per-wave coalesced: 32 lanes cover one row (512 B contiguous read,
  // 256 B contiguous write); 8 rows per pass; 16 passes in 4-pass chunks
  // (caps live float4 temps to keep VGPR under the (256,4) budget).
  {
    int rr = tid >> 5;        // 0..7: row within pass
    int c4 = (tid & 31) * 4;  // float4 column offset
    for (int pc = 0; pc < 4; pc++) {
#pragma unroll
      for (int p = 0; p < 4; p++) {
        int row = (pc * 4 + p) * 8 + rr;
        const float* src = w + (size_t)(row0 + row) * C + col0 + c4;
        float4 a = *(const float4*)src;
        const unsigned short* dl = &Dl[row * 136 + c4];
        short4v o;
        o[0] = (short)f2bf(a.x + bf2f(dl[0]));
        o[1] = (short)f2bf(a.y + bf2f(dl[1]));
        o[2] = (short)f2bf(a.z + bf2f(dl[2]));
        o[3] = (short)f2bf(a.w + bf2f(dl[3]));
        *(short4v*)(wb + (size_t)(row0 + row) * C + col0 + c4) = o;
      }
    }
  }
}

// ---------------- router (also writes Xb = bf16(x)) ----------------
__global__ __launch_bounds__(256) void k_router(
    const float* __restrict__ x, const float* __restrict__ gw,
    float* __restrict__ logits_out, int* __restrict__ sel,
    float* __restrict__ wtok, int* __restrict__ counts,
    unsigned short* __restrict__ xb) {
  int t = blockIdx.x;
  const float* xr = x + (size_t)t * HH;
  int base = threadIdx.x * 8;
  float4 x0 = *(const float4*)(xr + base);
  float4 x1 = *(const float4*)(xr + base + 4);
  {
    bf16x8 v;
    v[0] = (short)f2bf(x0.x); v[1] = (short)f2bf(x0.y);
    v[2] = (short)f2bf(x0.z); v[3] = (short)f2bf(x0.w);
    v[4] = (short)f2bf(x1.x); v[5] = (short)f2bf(x1.y);
    v[6] = (short)f2bf(x1.z); v[7] = (short)f2bf(x1.w);
    *(bf16x8*)(xb + (size_t)t * HH + base) = v;
  }
  float part[EE];
#pragma unroll
  for (int e = 0; e < EE; e++) {
    const float* g = gw + (size_t)e * HH + base;
    float4 g0 = *(const float4*)g;
    float4 g1 = *(const float4*)(g + 4);
    part[e] = x0.x * g0.x + x0.y * g0.y + x0.z * g0.z + x0.w * g0.w +
              x1.x * g1.x + x1.y * g1.y + x1.z * g1.z + x1.w * g1.w;
  }
#pragma unroll
  for (int off = 32; off > 0; off >>= 1)
#pragma unroll
    for (int e = 0; e < EE; e++) part[e] += __shfl_down(part[e], off);
  __shared__ float red[4][EE];
  int w = threadIdx.x >> 6, lane = threadIdx.x & 63;
  if (lane == 0) {
#pragma unroll
    for (int e = 0; e < EE; e++) red[w][e] = part[e];
  }
  __syncthreads();
  if (threadIdx.x == 0) {
    float lg[EE];
    float mx = -1e30f;
#pragma unroll
    for (int e = 0; e < EE; e++) {
      lg[e] = red[0][e] + red[1][e] + red[2][e] + red[3][e];
      logits_out[(size_t)t * EE + e] = lg[e];
      mx = fmaxf(mx, lg[e]);
    }
    float p[EE];
#pragma unroll
    for (int e = 0; e < EE; e++) p[e] = __expf(lg[e] - mx);
    int i0 = 0;
#pragma unroll
    for (int e = 1; e < EE; e++)
      if (lg[e] > lg[i0]) i0 = e;
    int i1 = (i0 == 0) ? 1 : 0;
#pragma unroll
    for (int e = 0; e < EE; e++)
      if (e != i0 && lg[e] > lg[i1]) i1 = e;
    float s = p[i0] + p[i1];
    sel[t * 2] = i0;
    sel[t * 2 + 1] = i1;
    wtok[t * 2] = p[i0] / s;
    wtok[t * 2 + 1] = p[i1] / s;
    atomicAdd(&counts[i0], 1);
    atomicAdd(&counts[i1], 1);
  }
}

// ---------------- prefix offsets ----------------
__global__ void k_offsets(const int* __restrict__ counts, int* __restrict__ offs,
                          int* __restrict__ curs) {
  if (threadIdx.x == 0 && blockIdx.x == 0) {
    int o = 0;
    for (int e = 0; e < EE; e++) {
      offs[e] = o;
      curs[e] = o;
      o += counts[e];
    }
    offs[EE] = o;
  }
}

// ---------------- build compact expert lists ----------------
__global__ void k_build(const int* __restrict__ sel, const float* __restrict__ wtok,
                        int* __restrict__ curs, int* __restrict__ rowsA,
                        float* __restrict__ rowwgt, int* __restrict__ rowid) {
  int t = blockIdx.x * blockDim.x + threadIdx.x;
  if (t >= TT) return;
  for (int k = 0; k < 2; k++) {
    int e = sel[t * 2 + k];
    int pos = atomicAdd(&curs[e], 1);
    rowsA[pos] = t;
    rowwgt[pos] = wtok[t * 2 + k];
    rowid[t * 2 + k] = pos;
  }
}

// ---------------- MLP1 dual: hmid = silu(X@W1'^T) * (X@W3'^T) ----------------
// All-DMA bf16 staging (proven structure), merged weights, no LR.
__global__ __launch_bounds__(256, 2) void k_mlp1(
    const unsigned short* __restrict__ Xb,
    const unsigned short* __restrict__ W1b, const unsigned short* __restrict__ W3b,
    unsigned short* __restrict__ hmid,
    const int* __restrict__ counts, const int* __restrict__ offs,
    const int* __restrict__ rowsA) {
  int e = blockIdx.z;
  int cnt = counts[e];
  int m0 = blockIdx.y * 128;
  if (m0 >= cnt) return;
  int n0 = blockIdx.x * 128;
  int roff = offs[e];
  __shared__ unsigned short As[128 * 64];
  __shared__ unsigned short Bg[128 * 64];
  __shared__ unsigned short Bu[128 * 64];
  int tid = threadIdx.x, lane = tid & 63, w = tid >> 6;
  int wr = (w >> 1) * 64, wc = (w & 1) * 64;
  f32x4 accg[4][4], accu[4][4];
#pragma unroll
  for (int m = 0; m < 4; m++)
#pragma unroll
    for (int n = 0; n < 4; n++) {
      accg[m][n] = (f32x4){0.f, 0.f, 0.f, 0.f};
      accu[m][n] = (f32x4){0.f, 0.f, 0.f, 0.f};
    }
  int srow = (w << 5) + (lane >> 3);
  int swz = (((lane & 7) ^ ((lane >> 3) & 7)) << 3);
  const unsigned short* pa[4];
  const unsigned short* pg[4];
  const unsigned short* pu[4];
  {
    const unsigned short* w1 = W1b + (size_t)e * II * HH;
    const unsigned short* w3 = W3b + (size_t)e * II * HH;
#pragma unroll
    for (int i = 0; i < 4; i++) {
      int gr = m0 + srow + i * 8;
      if (gr >= cnt) gr = cnt - 1;  // clamp: garbage rows masked at store
      pa[i] = Xb + (size_t)rowsA[roff + gr] * HH + swz;
      pg[i] = w1 + (size_t)(n0 + srow + i * 8) * HH + swz;
      pu[i] = w3 + (size_t)(n0 + srow + i * 8) * HH + swz;
    }
  }
  for (int kt = 0; kt < HH; kt += 64) {
#pragma unroll
    for (int i = 0; i < 4; i++) {
      gload16(pa[i] + kt, &As[((w << 5) + (i << 3)) * 64]);
      gload16(pg[i] + kt, &Bg[((w << 5) + (i << 3)) * 64]);
      gload16(pu[i] + kt, &Bu[((w << 5) + (i << 3)) * 64]);
    }
    __syncthreads();
#pragma unroll
    for (int ks = 0; ks < 2; ks++) {
      bf16x8 af[4], bg[4], bu[4];
#pragma unroll
      for (int m = 0; m < 4; m++) {
        int r = wr + m * 16 + (lane & 15);
        af[m] = *(const bf16x8*)&As[r * 64 + (((ks * 4 + (lane >> 4)) ^ (r & 7)) * 8)];
      }
#pragma unroll
      for (int n = 0; n < 4; n++) {
        int r = wc + n * 16 + (lane & 15);
        int idx = r * 64 + (((ks * 4 + (lane >> 4)) ^ (r & 7)) * 8);
        bg[n] = *(const bf16x8*)&Bg[idx];
        bu[n] = *(const bf16x8*)&Bu[idx];
      }
#pragma unroll
      for (int m = 0; m < 4; m++)
#pragma unroll
        for (int n = 0; n < 4; n++) {
          accg[m][n] = __builtin_amdgcn_mfma_f32_16x16x32_bf16(af[m], bg[n], accg[m][n], 0, 0, 0);
          accu[m][n] = __builtin_amdgcn_mfma_f32_16x16x32_bf16(af[m], bu[n], accu[m][n], 0, 0, 0);
        }
    }
    __syncthreads();
  }
  // epilogue: silu(g) * u -> bf16
#pragma unroll
  for (int m = 0; m < 4; m++) {
#pragma unroll
    for (int r4 = 0; r4 < 4; r4++) {
      int row = m0 + wr + m * 16 + (lane >> 4) * 4 + r4;
      if (row < cnt) {
        size_t rb = (size_t)(roff + row) * II + n0 + wc;
#pragma unroll
        for (int n = 0; n < 4; n++) {
          float g = accg[m][n][r4], uu = accu[m][n][r4];
          float h = (g / (1.f + __expf(-g))) * uu;
          hmid[rb + n * 16 + (lane & 15)] = f2bf(h);
        }
      }
    }
  }
}

// ---------------- MLP2: y = (hmid@W2'^T)*rowwgt -> ybuf (fp32), no LR ---------
__global__ __launch_bounds__(256, 2) void k_mlp2(
    const unsigned short* __restrict__ hmid,
    const unsigned short* __restrict__ W2b,
    const float* __restrict__ rowwgt, float* __restrict__ ybuf,
    const int* __restrict__ counts, const int* __restrict__ offs) {
  int e = blockIdx.z;
  int cnt = counts[e];
  int m0 = blockIdx.y * 128;
  if (m0 >= cnt) return;
  int n0 = blockIdx.x * 128;
  int roff = offs[e];
  __shared__ unsigned short As[128 * 64];
  __shared__ unsigned short Bs[128 * 64];
  int tid = threadIdx.x, lane = tid & 63, w = tid >> 6;
  int wr = (w >> 1) * 64, wc = (w & 1) * 64;
  f32x4 acc[4][4];
#pragma unroll
  for (int m = 0; m < 4; m++)
#pragma unroll
    for (int n = 0; n < 4; n++) acc[m][n] = (f32x4){0.f, 0.f, 0.f, 0.f};
  int srow = (w << 5) + (lane >> 3);
  int swz = (((lane & 7) ^ ((lane >> 3) & 7)) << 3);
  const unsigned short* pa[4];
  const unsigned short* pb[4];
  {
    const unsigned short* w2 = W2b + (size_t)e * HH * II;
#pragma unroll
    for (int i = 0; i < 4; i++) {
      int gr = m0 + srow + i * 8;
      if (gr >= cnt) gr = cnt - 1;
      pa[i] = hmid + (size_t)(roff + gr) * II + swz;
      pb[i] = w2 + (size_t)(n0 + srow + i * 8) * II + swz;
    }
  }
  for (int kt = 0; kt < II; kt += 64) {
#pragma unroll
    for (int i = 0; i < 4; i++) {
      gload16(pa[i] + kt, &As[((w << 5) + (i << 3)) * 64]);
      gload16(pb[i] + kt, &Bs[((w << 5) + (i << 3)) * 64]);
    }
    __syncthreads();
#pragma unroll
    for (int ks = 0; ks < 2; ks++) {
      bf16x8 af[4], bs[4];
#pragma unroll
      for (int m = 0; m < 4; m++) {
        int r = wr + m * 16 + (lane & 15);
        af[m] = *(const bf16x8*)&As[r * 64 + (((ks * 4 + (lane >> 4)) ^ (r & 7)) * 8)];
      }
#pragma unroll
      for (int n = 0; n < 4; n++) {
        int r = wc + n * 16 + (lane & 15);
        bs[n] = *(const bf16x8*)&Bs[r * 64 + (((ks * 4 + (lane >> 4)) ^ (r & 7)) * 8)];
      }
#pragma unroll
      for (int m = 0; m < 4; m++)
#pragma unroll
        for (int n = 0; n < 4; n++)
          acc[m][n] = __builtin_amdgcn_mfma_f32_16x16x32_bf16(af[m], bs[n], acc[m][n], 0, 0, 0);
    }
    __syncthreads();
  }
#pragma unroll
  for (int m = 0; m < 4; m++) {
#pragma unroll
    for (int r4 = 0; r4 < 4; r4++) {
      int row = m0 + wr + m * 16 + (lane >> 4) * 4 + r4;
      if (row < cnt) {
        float wgt = rowwgt[roff + row];
        size_t rb = (size_t)(roff + row) * HH + n0 + wc;
#pragma unroll
        for (int n = 0; n < 4; n++)
          ybuf[rb + n * 16 + (lane & 15)] = acc[m][n][r4] * wgt;
      }
    }
  }
}

// ---------------- combine: out[t] = y[row0] + y[row1] ----------------
__global__ void k_combine(const float* __restrict__ ybuf, const int* __restrict__ rowid,
                          float* __restrict__ out) {
  int idx = blockIdx.x * 256 + threadIdx.x;
  int t = idx >> 8;
  int c = (idx & 255) * 8;
  int r0 = rowid[t * 2], r1 = rowid[t * 2 + 1];
  const float* y0 = ybuf + (size_t)r0 * HH + c;
  const float* y1 = ybuf + (size_t)r1 * HH + c;
  float4 a0 = *(const float4*)y0, a1 = *(const float4*)(y0 + 4);
  float4 b0 = *(const float4*)y1, b1 = *(const float4*)(y1 + 4);
  float4 o0 = {a0.x + b0.x, a0.y + b0.y, a0.z + b0.z, a0.w + b0.w};
  float4 o1 = {a1.x + b1.x, a1.y + b1.y, a1.z + b1.z, a1.w + b1.w};
  float* o = out + (size_t)t * HH + c;
  *(float4*)o = o0;
  *(float4*)(o + 4) = o1;
}

extern "C" void kernel_launch(void* const* d_in, const int* in_sizes, int n_in,
                              void* d_out, int out_size, void* d_ws, size_t ws_size,
                              hipStream_t stream) {
  const float* x  = (const float*)d_in[0];
  const float* gw = (const float*)d_in[1];
  const float* W1 = (const float*)d_in[2];
  const float* W2 = (const float*)d_in[3];
  const float* W3 = (const float*)d_in[4];
  const float* U1 = (const float*)d_in[5];
  const float* V1 = (const float*)d_in[6];
  const float* U2 = (const float*)d_in[7];
  const float* V2 = (const float*)d_in[8];
  const float* U3 = (const float*)d_in[9];
  const float* V3 = (const float*)d_in[10];
  float* out = (float*)d_out;
  float* logits = out + (size_t)TT * HH;

  char* ws = (char*)d_ws;
  size_t off = 0;
  auto take = [&](size_t b) -> char* {
    char* p = ws + off;
    off += (b + 255) & ~(size_t)255;
    return p;
  };
  unsigned short* Xb   = (unsigned short*)take((size_t)TT * HH * 2);
  unsigned short* hmid = (unsigned short*)take((size_t)ROWS * II * 2);
  float* ybuf          = (float*)take((size_t)ROWS * HH * 4);
  int* sel             = (int*)take((size_t)TT * 2 * 4);
  float* wtok          = (float*)take((size_t)TT * 2 * 4);
  int* rowsA           = (int*)take((size_t)ROWS * 4);
  float* rowwgt        = (float*)take((size_t)ROWS * 4);
  int* rowid           = (int*)take((size_t)TT * 2 * 4);
  int* meta            = (int*)take(1024);
  int* counts  = meta;
  int* offs    = meta + 16;
  int* curs    = meta + 32;
  unsigned short* W1b = (unsigned short*)take((size_t)EE * II * HH * 2);
  unsigned short* W3b = (unsigned short*)take((size_t)EE * II * HH * 2);
  unsigned short* W2b = (unsigned short*)take((size_t)EE * HH * II * 2);
  unsigned short* V1b = (unsigned short*)take((size_t)EE * RR * HH * 2);
  unsigned short* V3b = (unsigned short*)take((size_t)EE * RR * HH * 2);
  unsigned short* V2b = (unsigned short*)take((size_t)EE * RR * II * 2);
  unsigned short* U1p = (unsigned short*)take((size_t)EE * II * RPAD * 2);
  unsigned short* U3p = (unsigned short*)take((size_t)EE * II * RPAD * 2);
  unsigned short* U2p = (unsigned short*)take((size_t)EE * HH * RPAD * 2);

  hipMemsetAsync(counts, 0, EE * sizeof(int), stream);
  // small preps: V -> bf16, U -> padded bf16
  k_f2bf_flat<<<1024, 256, 0, stream>>>(V1, V1b, (long long)EE * RR * HH / 8);
  k_f2bf_flat<<<1024, 256, 0, stream>>>(V3, V3b, (long long)EE * RR * HH / 8);
  k_f2bf_flat<<<1024, 256, 0, stream>>>(V2, V2b, (long long)EE * RR * II / 8);
  k_upad<<<(EE * II * 24 + 255) / 256, 256, 0, stream>>>(U1, U1p, EE * II);
  k_upad<<<(EE * II * 24 + 255) / 256, 256, 0, stream>>>(U3, U3p, EE * II);
  k_upad<<<(EE * HH * 24 + 255) / 256, 256, 0, stream>>>(U2, U2p, EE * HH);
  // merge low-rank delta into bf16 weights: W' = bf16(W + U@V)
  k_merge<<<dim3(HH / 128, II / 128, EE), 256, 0, stream>>>(W1, U1p, V1b, W1b, II, HH);
  k_merge<<<dim3(HH / 128, II / 128, EE), 256, 0, stream>>>(W3, U3p, V3b, W3b, II, HH);
  k_merge<<<dim3(II / 128, HH / 128, EE), 256, 0, stream>>>(W2, U2p, V2b, W2b, HH, II);
  // routing
  k_router<<<TT, 256, 0, stream>>>(x, gw, logits, sel, wtok, counts, Xb);
  k_offsets<<<1, 64, 0, stream>>>(counts, offs, curs);
  k_build<<<TT / 256, 256, 0, stream>>>(sel, wtok, curs, rowsA, rowwgt, rowid);
  // expert MLP (all-DMA bf16 GEMMs, merged weights, no low-rank machinery)
  k_mlp1<<<dim3(II / 128, TT / 128, EE), 256, 0, stream>>>(
      Xb, W1b, W3b, hmid, counts, offs, rowsA);
  k_mlp2<<<dim3(HH / 128, TT / 128, EE), 256, 0, stream>>>(
      hmid, W2b, rowwgt, ybuf, counts, offs);
  k_combine<<<(TT * HH / 8) / 256, 256, 0, stream>>>(ybuf, rowid, out);
}